// Round 6
// baseline (860.860 us; speedup 1.0000x reference)
//
#include <hip/hip_runtime.h>
#include <hip/hip_bf16.h>

// GCN layer: out = relu(D^-1/2 (A+I) D^-1/2 (x@W) + b)
// N=100000 nodes, E=1.6M edges, d_in=d_out=128, fp32.
//
// Pipeline (counting-sort CSR via 2-level bucketing, all write-amp-free):
//   K0 memset      : bcnt = 0                      (~1.5 KB)
//   K1 bin_count   : bucket histogram (LDS-aggregated, 256-node buckets)
//   K2 bin_scan    : bbase = exclusive_scan(bcnt)  (1 block)
//   K3 bin_scatter : bins[bcur[b]++] = (c&255)<<17 | r   (sequential per bucket)
//   K4 bucket_build: per bucket (1 block): LDS hist+scan -> cnt/offsets/dinv,
//                    LDS-cursor scatter -> srcidx  (16 KB L2-resident region)
//   K5 gemm_kernel : xw = x @ W (fp32, 8x8 reg tile) + bf16 mirror xwh
//   K6 accum_kernel: per node (1 wave): acc = dinv_i^2*xw[i](fp32)
//                    + sum_e dinv[r]*dinv_i*xwh[r](bf16); out = relu(acc + b)

#define BSHIFT 8              // 256 nodes per bucket
#define BNODES (1 << BSHIFT)

__device__ __forceinline__ void fma4(float4& acc, float s, const float4& v) {
  acc.x = fmaf(s, v.x, acc.x);
  acc.y = fmaf(s, v.y, acc.y);
  acc.z = fmaf(s, v.z, acc.z);
  acc.w = fmaf(s, v.w, acc.w);
}

__device__ __forceinline__ unsigned pack_bf16x2(float a, float b) {
  unsigned ua = __float_as_uint(a), ub = __float_as_uint(b);
  ua += 0x7FFFu + ((ua >> 16) & 1u);  // RNE
  ub += 0x7FFFu + ((ub >> 16) & 1u);
  return (ua >> 16) | (ub & 0xFFFF0000u);
}

// --- K1: bucket histogram, LDS-aggregated ---
__global__ __launch_bounds__(256) void bin_count(const int* __restrict__ col,
                                                 int* __restrict__ bcnt, int E, int NB) {
  __shared__ int h[512];
  for (int i = threadIdx.x; i < NB; i += 256) h[i] = 0;
  __syncthreads();
  int idx = blockIdx.x * blockDim.x + threadIdx.x;
  int stride = gridDim.x * blockDim.x;
  for (; idx < E; idx += stride) atomicAdd(&h[col[idx] >> BSHIFT], 1);
  __syncthreads();
  for (int i = threadIdx.x; i < NB; i += 256) {
    int v = h[i];
    if (v) atomicAdd(&bcnt[i], v);
  }
}

// --- K2: exclusive scan of bucket counts (NB <= 512), one block ---
__global__ __launch_bounds__(512) void bin_scan(const int* __restrict__ bcnt,
                                                int* __restrict__ bbase,
                                                int* __restrict__ bcur, int NB) {
  __shared__ int s[512];
  int tid = threadIdx.x;
  int v = (tid < NB) ? bcnt[tid] : 0;
  s[tid] = v;
  __syncthreads();
  for (int off = 1; off < 512; off <<= 1) {
    int t = (tid >= off) ? s[tid - off] : 0;
    __syncthreads();
    s[tid] += t;
    __syncthreads();
  }
  if (tid < NB) {
    int e = s[tid] - v;
    bbase[tid] = e;
    bcur[tid] = e;
    if (tid == NB - 1) bbase[NB] = s[tid];  // sentinel = E
  }
}

// --- K3: coarse scatter into bucket-ordered bins (sequential per bucket) ---
__global__ __launch_bounds__(256) void bin_scatter(const int* __restrict__ row,
                                                   const int* __restrict__ col,
                                                   int* __restrict__ bcur,
                                                   unsigned* __restrict__ bins, int E) {
  int idx = blockIdx.x * blockDim.x + threadIdx.x;
  int stride = gridDim.x * blockDim.x;
  for (; idx < E; idx += stride) {
    int c = col[idx];
    int r = row[idx];
    int p = atomicAdd(&bcur[c >> BSHIFT], 1);
    bins[p] = ((unsigned)(c & (BNODES - 1)) << 17) | (unsigned)r;
  }
}

// --- K4: per-bucket CSR build, everything in LDS ---
__global__ __launch_bounds__(256) void bucket_build(const unsigned* __restrict__ bins,
                                                    const int* __restrict__ bbase,
                                                    int* __restrict__ cnt,
                                                    int* __restrict__ offsets,
                                                    float* __restrict__ dinv,
                                                    int* __restrict__ srcidx, int N) {
  int b = blockIdx.x;
  int base = bbase[b];
  int nItems = bbase[b + 1] - base;
  __shared__ int h[BNODES];
  __shared__ int sc[BNODES];
  __shared__ int cur[BNODES];
  int tid = threadIdx.x;
  h[tid] = 0;
  __syncthreads();
  for (int i = tid; i < nItems; i += 256) atomicAdd(&h[bins[base + i] >> 17], 1);
  __syncthreads();
  int v = h[tid];
  sc[tid] = v;
  __syncthreads();
  for (int off = 1; off < 256; off <<= 1) {
    int t = (tid >= off) ? sc[tid - off] : 0;
    __syncthreads();
    sc[tid] += t;
    __syncthreads();
  }
  int excl = sc[tid] - v;
  cur[tid] = excl;
  int node = (b << BSHIFT) + tid;
  if (node < N) {
    cnt[node] = v;
    offsets[node] = base + excl;
    dinv[node] = rsqrtf((float)(v + 1));
  }
  __syncthreads();
  for (int i = tid; i < nItems; i += 256) {
    unsigned x = bins[base + i];
    int clow = x >> 17;
    int r = (int)(x & 0x1FFFFu);
    int p = atomicAdd(&cur[clow], 1);
    srcidx[base + p] = r;
  }
}

// --- K5: xw = x @ W (8x8 register tile) + optional bf16 mirror ---
__global__ __launch_bounds__(256) void gemm_kernel(const float* __restrict__ x,
                                                   const float* __restrict__ W,
                                                   float* __restrict__ xw,
                                                   unsigned short* __restrict__ xwh, int M) {
  __shared__ float xs[128 * 32];  // swizzled
  __shared__ float Wl[32 * 128];
  int tid = threadIdx.x;
  int rg = tid >> 4;
  int cg = tid & 15;
  int rowBase = blockIdx.x * 128;

  float4 acc0[8], acc1[8];
#pragma unroll
  for (int j = 0; j < 8; ++j) {
    acc0[j] = make_float4(0.f, 0.f, 0.f, 0.f);
    acc1[j] = make_float4(0.f, 0.f, 0.f, 0.f);
  }

  for (int kc = 0; kc < 4; ++kc) {
#pragma unroll
    for (int m = 0; m < 4; ++m) {
      int l = tid + 256 * m;
      int r = l >> 3;
      int u = l & 7;
      int gr = rowBase + r;
      float4 v = make_float4(0.f, 0.f, 0.f, 0.f);
      if (gr < M) v = *(const float4*)&x[(size_t)gr * 128 + kc * 32 + u * 4];
      int swz = u ^ ((r >> 3) & 7);
      *(float4*)&xs[r * 32 + swz * 4] = v;
    }
#pragma unroll
    for (int m = 0; m < 4; ++m) {
      int l = tid + 256 * m;
      int k = l >> 5;
      int u = l & 31;
      *(float4*)&Wl[k * 128 + u * 4] = *(const float4*)&W[(size_t)(kc * 32 + k) * 128 + u * 4];
    }
    __syncthreads();

#pragma unroll
    for (int k4 = 0; k4 < 32; k4 += 4) {
      float4 xa[8];
      int swz = (k4 >> 2) ^ (rg & 7);
#pragma unroll
      for (int j = 0; j < 8; ++j) {
        xa[j] = *(float4*)&xs[(rg * 8 + j) * 32 + swz * 4];
      }
#pragma unroll
      for (int kk = 0; kk < 4; ++kk) {
        float4 wb0 = *(float4*)&Wl[(k4 + kk) * 128 + cg * 8];
        float4 wb1 = *(float4*)&Wl[(k4 + kk) * 128 + cg * 8 + 4];
#pragma unroll
        for (int j = 0; j < 8; ++j) {
          float s = (kk == 0) ? xa[j].x : (kk == 1) ? xa[j].y : (kk == 2) ? xa[j].z : xa[j].w;
          fma4(acc0[j], s, wb0);
          fma4(acc1[j], s, wb1);
        }
      }
    }
    __syncthreads();
  }

#pragma unroll
  for (int j = 0; j < 8; ++j) {
    int gr = rowBase + rg * 8 + j;
    if (gr < M) {
      *(float4*)&xw[(size_t)gr * 128 + cg * 8] = acc0[j];
      *(float4*)&xw[(size_t)gr * 128 + cg * 8 + 4] = acc1[j];
      if (xwh) {
        uint4 p;
        p.x = pack_bf16x2(acc0[j].x, acc0[j].y);
        p.y = pack_bf16x2(acc0[j].z, acc0[j].w);
        p.z = pack_bf16x2(acc1[j].x, acc1[j].y);
        p.w = pack_bf16x2(acc1[j].z, acc1[j].w);
        *(uint4*)&xwh[(size_t)gr * 128 + cg * 8] = p;
      }
    }
  }
}

// --- K6: per-node gather-accumulate (1 wave per node) ---
template <int USE_BF16>
__global__ __launch_bounds__(256) void accum_kernel(const float* __restrict__ xw,
                                                    const unsigned short* __restrict__ xwh,
                                                    const int* __restrict__ srcidx,
                                                    const int* __restrict__ offsets,
                                                    const int* __restrict__ cnt,
                                                    const float* __restrict__ dinv,
                                                    const float* __restrict__ bias,
                                                    float* __restrict__ out, int N) {
  int wave = (int)(blockIdx.x * (blockDim.x >> 6)) + (threadIdx.x >> 6);
  int lane = threadIdx.x & 63;
  if (wave >= N) return;
  int i = wave;
  float di = dinv[i];
  int off = offsets[i];
  int deg = cnt[i];

  // self-loop term in fp32 (norm = dinv_i^2 can be 1.0 for isolated nodes)
  const float2* xws = (const float2*)(xw + (size_t)i * 128);
  float2 self = xws[lane];
  float sn = di * di;
  float2 acc;
  acc.x = self.x * sn;
  acc.y = self.y * sn;

  int j = 0;
  while (j < deg) {
    int batch = min(64, deg - j);
    int r = 0;
    float dv = 0.f;
    if (lane < batch) {
      r = srcidx[off + j + lane];
      dv = dinv[r];
    }
    for (int t = 0; t < batch; ++t) {
      int rs = __shfl(r, t);
      float norm = __shfl(dv, t) * di;
      if (USE_BF16) {
        const unsigned* xr = (const unsigned*)(xwh + (size_t)rs * 128);
        unsigned v = xr[lane];
        acc.x = fmaf(__uint_as_float(v << 16), norm, acc.x);
        acc.y = fmaf(__uint_as_float(v & 0xFFFF0000u), norm, acc.y);
      } else {
        const float2* xr = (const float2*)(xw + (size_t)rs * 128);
        float2 v = xr[lane];
        acc.x = fmaf(v.x, norm, acc.x);
        acc.y = fmaf(v.y, norm, acc.y);
      }
    }
    j += batch;
  }

  float2 bb = ((const float2*)bias)[lane];
  acc.x = fmaxf(acc.x + bb.x, 0.f);
  acc.y = fmaxf(acc.y + bb.y, 0.f);
  ((float2*)(out + (size_t)i * 128))[lane] = acc;
}

extern "C" void kernel_launch(void* const* d_in, const int* in_sizes, int n_in,
                              void* d_out, int out_size, void* d_ws, size_t ws_size,
                              hipStream_t stream) {
  const float* x = (const float*)d_in[0];
  const int* edge = (const int*)d_in[1];
  const float* W = (const float*)d_in[2];
  const float* b = (const float*)d_in[3];
  float* out = (float*)d_out;

  int N = in_sizes[0] / 128;  // 100000
  int E = in_sizes[1] / 2;    // 1600000
  const int* row = edge;      // sources
  const int* col = edge + E;  // targets
  int NB = (N + BNODES - 1) >> BSHIFT;  // 391

  // workspace layout
  char* ws = (char*)d_ws;
  size_t off = 0;
  auto alloc = [&](size_t bytes) -> void* {
    off = (off + 255) & ~(size_t)255;
    void* p = ws + off;
    off += bytes;
    return p;
  };
  float* xw = (float*)alloc((size_t)N * 128 * sizeof(float));  // 51.2 MB
  int* cnt = (int*)alloc((size_t)N * sizeof(int));
  int* offs = (int*)alloc((size_t)N * sizeof(int));
  float* dinv = (float*)alloc((size_t)N * sizeof(float));
  int* srcidx = (int*)alloc((size_t)E * sizeof(int));
  int* bcnt = (int*)alloc((size_t)(NB + 1) * sizeof(int));
  int* bbase = (int*)alloc((size_t)(NB + 1) * sizeof(int));
  int* bcur = (int*)alloc((size_t)(NB + 1) * sizeof(int));
  // bins aliases xw: bins live K3->K4, xw live K5->K6 (stream-serial => safe)
  unsigned* bins = (unsigned*)xw;
  // bf16 mirror, only if workspace allows
  size_t need_xwh = ((off + 255) & ~(size_t)255) + (size_t)N * 128 * sizeof(unsigned short);
  unsigned short* xwh = nullptr;
  if (ws_size >= need_xwh) xwh = (unsigned short*)alloc((size_t)N * 128 * sizeof(unsigned short));

  (void)hipMemsetAsync(bcnt, 0, (size_t)(NB + 1) * sizeof(int), stream);
  bin_count<<<256, 256, 0, stream>>>(col, bcnt, E, NB);
  bin_scan<<<1, 512, 0, stream>>>(bcnt, bbase, bcur, NB);
  bin_scatter<<<1024, 256, 0, stream>>>(row, col, bcur, bins, E);
  bucket_build<<<NB, 256, 0, stream>>>(bins, bbase, cnt, offs, dinv, srcidx, N);

  int gblocks = (N + 127) / 128;
  gemm_kernel<<<gblocks, 256, 0, stream>>>(x, W, xw, xwh, N);

  int nblocks = (N + 3) / 4;  // 4 waves per 256-thread block
  if (xwh)
    accum_kernel<1><<<nblocks, 256, 0, stream>>>(xw, xwh, srcidx, offs, cnt, dinv, b, out, N);
  else
    accum_kernel<0><<<nblocks, 256, 0, stream>>>(xw, xwh, srcidx, offs, cnt, dinv, b, out, N);
}

// Round 7
// 480.204 us; speedup vs baseline: 1.7927x; 1.7927x over previous
//
#include <hip/hip_runtime.h>
#include <hip/hip_bf16.h>

// GCN layer: out = relu(D^-1/2 (A+I) D^-1/2 (x@W) + b)
// N=100000 nodes, E=1.6M edges, d_in=d_out=128, fp32.
//
// Pipeline (atomic-free counting-sort CSR via 2D histogram):
//   K1 hist2d      : per-block LDS hist of 391 buckets -> hist2d[bucket][block]
//   K2 scan2d      : exclusive scan of hist2d (bucket-major, in-place, 1 block)
//                    -> per-(block,bucket) reserved ranges + bbase[]
//   K3 scatter2    : block re-reads its chunk, scatters via LDS cursors into
//                    bins (contiguous runs, write-amp ~1, ZERO global atomics)
//   K4 bucket_build: per bucket (1 block): LDS hist+scan -> cnt/offsets/dinv,
//                    LDS-cursor scatter -> srcidx
//   K5 gemm_kernel : xw = x @ W (fp32, 8x8 reg tile) + bf16 mirror xwh
//   K6 accum_kernel: per node (1 wave): acc = dinv_i^2*xw[i](fp32)
//                    + sum_e dinv[r]*dinv_i*xwh[r](bf16); out = relu(acc + b)

#define BSHIFT 8              // 256 nodes per bucket
#define BNODES (1 << BSHIFT)
#define NB_MAX 512
#define NBLK 256              // scatter blocks (runs of ~16 elems = 1 cacheline)

__device__ __forceinline__ void fma4(float4& acc, float s, const float4& v) {
  acc.x = fmaf(s, v.x, acc.x);
  acc.y = fmaf(s, v.y, acc.y);
  acc.z = fmaf(s, v.z, acc.z);
  acc.w = fmaf(s, v.w, acc.w);
}

__device__ __forceinline__ unsigned pack_bf16x2(float a, float b) {
  unsigned ua = __float_as_uint(a), ub = __float_as_uint(b);
  ua += 0x7FFFu + ((ua >> 16) & 1u);  // RNE
  ub += 0x7FFFu + ((ub >> 16) & 1u);
  return (ua >> 16) | (ub & 0xFFFF0000u);
}

// --- K1: per-block bucket histogram -> hist2d[bucket*NBLK + block] ---
__global__ __launch_bounds__(256) void hist2d_kernel(const int* __restrict__ col,
                                                     int* __restrict__ hist2d,
                                                     int E, int NB, int chunk) {
  __shared__ int h[NB_MAX];
  int j = blockIdx.x;
  int lo = j * chunk;
  int hi = min(lo + chunk, E);
  for (int i = threadIdx.x; i < NB; i += 256) h[i] = 0;
  __syncthreads();
  for (int idx = lo + threadIdx.x; idx < hi; idx += 256)
    atomicAdd(&h[col[idx] >> BSHIFT], 1);
  __syncthreads();
  for (int i = threadIdx.x; i < NB; i += 256) hist2d[i * NBLK + j] = h[i];
}

// --- K2: exclusive scan of hist2d (M = NB*NBLK values), in place; bbase out ---
__global__ __launch_bounds__(1024) void scan2d_kernel(int* __restrict__ hist2d,
                                                      int* __restrict__ bbase,
                                                      int NB, int E) {
  __shared__ int s[1024];
  int tid = threadIdx.x;
  int M = NB * NBLK;
  int per = (M + 1023) / 1024;
  int start = tid * per;
  int end = min(start + per, M);
  int sum = 0;
  for (int i = start; i < end; ++i) sum += hist2d[i];
  s[tid] = sum;
  __syncthreads();
  for (int off = 1; off < 1024; off <<= 1) {
    int t = (tid >= off) ? s[tid - off] : 0;
    __syncthreads();
    s[tid] += t;
    __syncthreads();
  }
  int run = s[tid] - sum;  // exclusive prefix of this thread's span
  for (int i = start; i < end; ++i) {
    int v = hist2d[i];
    hist2d[i] = run;
    run += v;
  }
  __syncthreads();
  for (int i = tid; i < NB; i += 1024) bbase[i] = hist2d[i * NBLK];
  if (tid == 0) bbase[NB] = E;  // sentinel
}

// --- K3: atomic-free scatter using reserved per-(block,bucket) ranges ---
__global__ __launch_bounds__(256) void scatter2_kernel(const int* __restrict__ row,
                                                       const int* __restrict__ col,
                                                       const int* __restrict__ hist2d,
                                                       unsigned* __restrict__ bins,
                                                       int E, int NB, int chunk) {
  __shared__ int cur[NB_MAX];
  int j = blockIdx.x;
  int lo = j * chunk;
  int hi = min(lo + chunk, E);
  for (int i = threadIdx.x; i < NB; i += 256) cur[i] = hist2d[i * NBLK + j];
  __syncthreads();
  for (int idx = lo + threadIdx.x; idx < hi; idx += 256) {
    int c = col[idx];
    int r = row[idx];
    int p = atomicAdd(&cur[c >> BSHIFT], 1);  // LDS atomic only
    bins[p] = ((unsigned)(c & (BNODES - 1)) << 17) | (unsigned)r;
  }
}

// --- K4: per-bucket CSR build, everything in LDS ---
__global__ __launch_bounds__(256) void bucket_build(const unsigned* __restrict__ bins,
                                                    const int* __restrict__ bbase,
                                                    int* __restrict__ cnt,
                                                    int* __restrict__ offsets,
                                                    float* __restrict__ dinv,
                                                    int* __restrict__ srcidx, int N) {
  int b = blockIdx.x;
  int base = bbase[b];
  int nItems = bbase[b + 1] - base;
  __shared__ int h[BNODES];
  __shared__ int sc[BNODES];
  __shared__ int cur[BNODES];
  int tid = threadIdx.x;
  h[tid] = 0;
  __syncthreads();
  for (int i = tid; i < nItems; i += 256) atomicAdd(&h[bins[base + i] >> 17], 1);
  __syncthreads();
  int v = h[tid];
  sc[tid] = v;
  __syncthreads();
  for (int off = 1; off < 256; off <<= 1) {
    int t = (tid >= off) ? sc[tid - off] : 0;
    __syncthreads();
    sc[tid] += t;
    __syncthreads();
  }
  int excl = sc[tid] - v;
  cur[tid] = excl;
  int node = (b << BSHIFT) + tid;
  if (node < N) {
    cnt[node] = v;
    offsets[node] = base + excl;
    dinv[node] = rsqrtf((float)(v + 1));
  }
  __syncthreads();
  for (int i = tid; i < nItems; i += 256) {
    unsigned x = bins[base + i];
    int clow = x >> 17;
    int r = (int)(x & 0x1FFFFu);
    int p = atomicAdd(&cur[clow], 1);
    srcidx[base + p] = r;
  }
}

// --- K5: xw = x @ W (8x8 register tile) + optional bf16 mirror ---
__global__ __launch_bounds__(256) void gemm_kernel(const float* __restrict__ x,
                                                   const float* __restrict__ W,
                                                   float* __restrict__ xw,
                                                   unsigned short* __restrict__ xwh, int M) {
  __shared__ float xs[128 * 32];  // swizzled
  __shared__ float Wl[32 * 128];
  int tid = threadIdx.x;
  int rg = tid >> 4;
  int cg = tid & 15;
  int rowBase = blockIdx.x * 128;

  float4 acc0[8], acc1[8];
#pragma unroll
  for (int j = 0; j < 8; ++j) {
    acc0[j] = make_float4(0.f, 0.f, 0.f, 0.f);
    acc1[j] = make_float4(0.f, 0.f, 0.f, 0.f);
  }

  for (int kc = 0; kc < 4; ++kc) {
#pragma unroll
    for (int m = 0; m < 4; ++m) {
      int l = tid + 256 * m;
      int r = l >> 3;
      int u = l & 7;
      int gr = rowBase + r;
      float4 v = make_float4(0.f, 0.f, 0.f, 0.f);
      if (gr < M) v = *(const float4*)&x[(size_t)gr * 128 + kc * 32 + u * 4];
      int swz = u ^ ((r >> 3) & 7);
      *(float4*)&xs[r * 32 + swz * 4] = v;
    }
#pragma unroll
    for (int m = 0; m < 4; ++m) {
      int l = tid + 256 * m;
      int k = l >> 5;
      int u = l & 31;
      *(float4*)&Wl[k * 128 + u * 4] = *(const float4*)&W[(size_t)(kc * 32 + k) * 128 + u * 4];
    }
    __syncthreads();

#pragma unroll
    for (int k4 = 0; k4 < 32; k4 += 4) {
      float4 xa[8];
      int swz = (k4 >> 2) ^ (rg & 7);
#pragma unroll
      for (int j = 0; j < 8; ++j) {
        xa[j] = *(float4*)&xs[(rg * 8 + j) * 32 + swz * 4];
      }
#pragma unroll
      for (int kk = 0; kk < 4; ++kk) {
        float4 wb0 = *(float4*)&Wl[(k4 + kk) * 128 + cg * 8];
        float4 wb1 = *(float4*)&Wl[(k4 + kk) * 128 + cg * 8 + 4];
#pragma unroll
        for (int j = 0; j < 8; ++j) {
          float s = (kk == 0) ? xa[j].x : (kk == 1) ? xa[j].y : (kk == 2) ? xa[j].z : xa[j].w;
          fma4(acc0[j], s, wb0);
          fma4(acc1[j], s, wb1);
        }
      }
    }
    __syncthreads();
  }

#pragma unroll
  for (int j = 0; j < 8; ++j) {
    int gr = rowBase + rg * 8 + j;
    if (gr < M) {
      *(float4*)&xw[(size_t)gr * 128 + cg * 8] = acc0[j];
      *(float4*)&xw[(size_t)gr * 128 + cg * 8 + 4] = acc1[j];
      if (xwh) {
        uint4 p;
        p.x = pack_bf16x2(acc0[j].x, acc0[j].y);
        p.y = pack_bf16x2(acc0[j].z, acc0[j].w);
        p.z = pack_bf16x2(acc1[j].x, acc1[j].y);
        p.w = pack_bf16x2(acc1[j].z, acc1[j].w);
        *(uint4*)&xwh[(size_t)gr * 128 + cg * 8] = p;
      }
    }
  }
}

// --- K6: per-node gather-accumulate (1 wave per node) ---
template <int USE_BF16>
__global__ __launch_bounds__(256) void accum_kernel(const float* __restrict__ xw,
                                                    const unsigned short* __restrict__ xwh,
                                                    const int* __restrict__ srcidx,
                                                    const int* __restrict__ offsets,
                                                    const int* __restrict__ cnt,
                                                    const float* __restrict__ dinv,
                                                    const float* __restrict__ bias,
                                                    float* __restrict__ out, int N) {
  int wave = (int)(blockIdx.x * (blockDim.x >> 6)) + (threadIdx.x >> 6);
  int lane = threadIdx.x & 63;
  if (wave >= N) return;
  int i = wave;
  float di = dinv[i];
  int off = offsets[i];
  int deg = cnt[i];

  // self-loop term in fp32 (norm = dinv_i^2 can be 1.0 for isolated nodes)
  const float2* xws = (const float2*)(xw + (size_t)i * 128);
  float2 self = xws[lane];
  float sn = di * di;
  float2 acc;
  acc.x = self.x * sn;
  acc.y = self.y * sn;

  int j = 0;
  while (j < deg) {
    int batch = min(64, deg - j);
    int r = 0;
    float dv = 0.f;
    if (lane < batch) {
      r = srcidx[off + j + lane];
      dv = dinv[r];
    }
    for (int t = 0; t < batch; ++t) {
      int rs = __shfl(r, t);
      float norm = __shfl(dv, t) * di;
      if (USE_BF16) {
        const unsigned* xr = (const unsigned*)(xwh + (size_t)rs * 128);
        unsigned v = xr[lane];
        acc.x = fmaf(__uint_as_float(v << 16), norm, acc.x);
        acc.y = fmaf(__uint_as_float(v & 0xFFFF0000u), norm, acc.y);
      } else {
        const float2* xr = (const float2*)(xw + (size_t)rs * 128);
        float2 v = xr[lane];
        acc.x = fmaf(v.x, norm, acc.x);
        acc.y = fmaf(v.y, norm, acc.y);
      }
    }
    j += batch;
  }

  float2 bb = ((const float2*)bias)[lane];
  acc.x = fmaxf(acc.x + bb.x, 0.f);
  acc.y = fmaxf(acc.y + bb.y, 0.f);
  ((float2*)(out + (size_t)i * 128))[lane] = acc;
}

extern "C" void kernel_launch(void* const* d_in, const int* in_sizes, int n_in,
                              void* d_out, int out_size, void* d_ws, size_t ws_size,
                              hipStream_t stream) {
  const float* x = (const float*)d_in[0];
  const int* edge = (const int*)d_in[1];
  const float* W = (const float*)d_in[2];
  const float* b = (const float*)d_in[3];
  float* out = (float*)d_out;

  int N = in_sizes[0] / 128;  // 100000
  int E = in_sizes[1] / 2;    // 1600000
  const int* row = edge;      // sources
  const int* col = edge + E;  // targets
  int NB = (N + BNODES - 1) >> BSHIFT;  // 391 (<= NB_MAX)
  int chunk = (E + NBLK - 1) / NBLK;    // 6250

  // workspace layout
  char* ws = (char*)d_ws;
  size_t off = 0;
  auto alloc = [&](size_t bytes) -> void* {
    off = (off + 255) & ~(size_t)255;
    void* p = ws + off;
    off += bytes;
    return p;
  };
  float* xw = (float*)alloc((size_t)N * 128 * sizeof(float));  // 51.2 MB
  int* cnt = (int*)alloc((size_t)N * sizeof(int));
  int* offs = (int*)alloc((size_t)N * sizeof(int));
  float* dinv = (float*)alloc((size_t)N * sizeof(float));
  int* srcidx = (int*)alloc((size_t)E * sizeof(int));
  int* hist2d = (int*)alloc((size_t)NB * NBLK * sizeof(int));  // 400 KB
  int* bbase = (int*)alloc((size_t)(NB + 1) * sizeof(int));
  // bins aliases xw: bins live K3->K4, xw live K5->K6 (stream-serial => safe)
  unsigned* bins = (unsigned*)xw;
  // bf16 mirror, only if workspace allows
  size_t need_xwh = ((off + 255) & ~(size_t)255) + (size_t)N * 128 * sizeof(unsigned short);
  unsigned short* xwh = nullptr;
  if (ws_size >= need_xwh) xwh = (unsigned short*)alloc((size_t)N * 128 * sizeof(unsigned short));

  hist2d_kernel<<<NBLK, 256, 0, stream>>>(col, hist2d, E, NB, chunk);
  scan2d_kernel<<<1, 1024, 0, stream>>>(hist2d, bbase, NB, E);
  scatter2_kernel<<<NBLK, 256, 0, stream>>>(row, col, hist2d, bins, E, NB, chunk);
  bucket_build<<<NB, 256, 0, stream>>>(bins, bbase, cnt, offs, dinv, srcidx, N);

  int gblocks = (N + 127) / 128;
  gemm_kernel<<<gblocks, 256, 0, stream>>>(x, W, xw, xwh, N);

  int nblocks = (N + 3) / 4;  // 4 waves per 256-thread block
  if (xwh)
    accum_kernel<1><<<nblocks, 256, 0, stream>>>(xw, xwh, srcidx, offs, cnt, dinv, b, out, N);
  else
    accum_kernel<0><<<nblocks, 256, 0, stream>>>(xw, xwh, srcidx, offs, cnt, dinv, b, out, N);
}

// Round 8
// 314.815 us; speedup vs baseline: 2.7345x; 1.5254x over previous
//
#include <hip/hip_runtime.h>
#include <hip/hip_bf16.h>

// GCN layer: out = relu(D^-1/2 (A+I) D^-1/2 (x@W) + b)
// N=100000 nodes, E=1.6M edges, d_in=d_out=128, fp32.
//
// Pipeline (atomic-free counting-sort CSR via 2D histogram, parallel scans):
//   K1 hist2d      : per-block LDS hist of 391 buckets -> hist2d[bucket][block]
//   K2a scan_bucket: per-bucket (391 blocks) exclusive scan of its 256 block
//                    counts (in-place) + bucket total -> btot
//   K2b scan_btot  : exclusive scan of 391 bucket totals -> bbase (1 block)
//   K3 scatter2    : block re-reads its chunk, scatters via LDS cursors
//                    (bbase[b] + within-bucket prefix), ZERO global atomics
//   K4 bucket_build: per bucket (1 block): LDS hist+scan -> cnt/offsets/dinv,
//                    LDS-cursor scatter -> srcidx
//   K5 gemm_kernel : xw = x @ W (fp32, 8x8 reg tile) + bf16 mirror xwh
//   K6 accum_kernel: per node (1 wave): acc = dinv_i^2*xw[i](fp32)
//                    + sum_e dinv[r]*dinv_i*xwh[r](bf16); out = relu(acc + b)

#define BSHIFT 8              // 256 nodes per bucket
#define BNODES (1 << BSHIFT)
#define NB_MAX 512
#define NBLK 256              // scatter blocks (runs of ~16 elems = 1 cacheline)

__device__ __forceinline__ void fma4(float4& acc, float s, const float4& v) {
  acc.x = fmaf(s, v.x, acc.x);
  acc.y = fmaf(s, v.y, acc.y);
  acc.z = fmaf(s, v.z, acc.z);
  acc.w = fmaf(s, v.w, acc.w);
}

__device__ __forceinline__ unsigned pack_bf16x2(float a, float b) {
  unsigned ua = __float_as_uint(a), ub = __float_as_uint(b);
  ua += 0x7FFFu + ((ua >> 16) & 1u);  // RNE
  ub += 0x7FFFu + ((ub >> 16) & 1u);
  return (ua >> 16) | (ub & 0xFFFF0000u);
}

// --- K1: per-block bucket histogram -> hist2d[bucket*NBLK + block] ---
__global__ __launch_bounds__(256) void hist2d_kernel(const int* __restrict__ col,
                                                     int* __restrict__ hist2d,
                                                     int E, int NB, int chunk) {
  __shared__ int h[NB_MAX];
  int j = blockIdx.x;
  int lo = j * chunk;
  int hi = min(lo + chunk, E);
  for (int i = threadIdx.x; i < NB; i += 256) h[i] = 0;
  __syncthreads();
  for (int idx = lo + threadIdx.x; idx < hi; idx += 256)
    atomicAdd(&h[col[idx] >> BSHIFT], 1);
  __syncthreads();
  for (int i = threadIdx.x; i < NB; i += 256) hist2d[i * NBLK + j] = h[i];
}

// --- K2a: per-bucket exclusive scan over its 256 block counts (in place) ---
__global__ __launch_bounds__(256) void scan_bucket(int* __restrict__ hist2d,
                                                   int* __restrict__ btot) {
  __shared__ int s[256];
  int b = blockIdx.x;
  int tid = threadIdx.x;
  int v = hist2d[b * NBLK + tid];
  s[tid] = v;
  __syncthreads();
  for (int off = 1; off < 256; off <<= 1) {
    int t = (tid >= off) ? s[tid - off] : 0;
    __syncthreads();
    s[tid] += t;
    __syncthreads();
  }
  hist2d[b * NBLK + tid] = s[tid] - v;  // exclusive within-bucket prefix
  if (tid == 255) btot[b] = s[tid];
}

// --- K2b: exclusive scan of bucket totals -> bbase (+ sentinel) ---
__global__ __launch_bounds__(512) void scan_btot(const int* __restrict__ btot,
                                                 int* __restrict__ bbase, int NB, int E) {
  __shared__ int s[512];
  int tid = threadIdx.x;
  int v = (tid < NB) ? btot[tid] : 0;
  s[tid] = v;
  __syncthreads();
  for (int off = 1; off < 512; off <<= 1) {
    int t = (tid >= off) ? s[tid - off] : 0;
    __syncthreads();
    s[tid] += t;
    __syncthreads();
  }
  if (tid < NB) bbase[tid] = s[tid] - v;
  if (tid == 0) bbase[NB] = E;  // sentinel
}

// --- K3: atomic-free scatter using reserved per-(block,bucket) ranges ---
__global__ __launch_bounds__(256) void scatter2_kernel(const int* __restrict__ row,
                                                       const int* __restrict__ col,
                                                       const int* __restrict__ hist2d,
                                                       const int* __restrict__ bbase,
                                                       unsigned* __restrict__ bins,
                                                       int E, int NB, int chunk) {
  __shared__ int cur[NB_MAX];
  int j = blockIdx.x;
  int lo = j * chunk;
  int hi = min(lo + chunk, E);
  for (int i = threadIdx.x; i < NB; i += 256)
    cur[i] = bbase[i] + hist2d[i * NBLK + j];
  __syncthreads();
  for (int idx = lo + threadIdx.x; idx < hi; idx += 256) {
    int c = col[idx];
    int r = row[idx];
    int p = atomicAdd(&cur[c >> BSHIFT], 1);  // LDS atomic only
    bins[p] = ((unsigned)(c & (BNODES - 1)) << 17) | (unsigned)r;
  }
}

// --- K4: per-bucket CSR build, everything in LDS ---
__global__ __launch_bounds__(256) void bucket_build(const unsigned* __restrict__ bins,
                                                    const int* __restrict__ bbase,
                                                    int* __restrict__ cnt,
                                                    int* __restrict__ offsets,
                                                    float* __restrict__ dinv,
                                                    int* __restrict__ srcidx, int N) {
  int b = blockIdx.x;
  int base = bbase[b];
  int nItems = bbase[b + 1] - base;
  __shared__ int h[BNODES];
  __shared__ int sc[BNODES];
  __shared__ int cur[BNODES];
  int tid = threadIdx.x;
  h[tid] = 0;
  __syncthreads();
  for (int i = tid; i < nItems; i += 256) atomicAdd(&h[bins[base + i] >> 17], 1);
  __syncthreads();
  int v = h[tid];
  sc[tid] = v;
  __syncthreads();
  for (int off = 1; off < 256; off <<= 1) {
    int t = (tid >= off) ? sc[tid - off] : 0;
    __syncthreads();
    sc[tid] += t;
    __syncthreads();
  }
  int excl = sc[tid] - v;
  cur[tid] = excl;
  int node = (b << BSHIFT) + tid;
  if (node < N) {
    cnt[node] = v;
    offsets[node] = base + excl;
    dinv[node] = rsqrtf((float)(v + 1));
  }
  __syncthreads();
  for (int i = tid; i < nItems; i += 256) {
    unsigned x = bins[base + i];
    int clow = x >> 17;
    int r = (int)(x & 0x1FFFFu);
    int p = atomicAdd(&cur[clow], 1);
    srcidx[base + p] = r;
  }
}

// --- K5: xw = x @ W (8x8 register tile) + optional bf16 mirror ---
__global__ __launch_bounds__(256) void gemm_kernel(const float* __restrict__ x,
                                                   const float* __restrict__ W,
                                                   float* __restrict__ xw,
                                                   unsigned short* __restrict__ xwh, int M) {
  __shared__ float xs[128 * 32];  // swizzled
  __shared__ float Wl[32 * 128];
  int tid = threadIdx.x;
  int rg = tid >> 4;
  int cg = tid & 15;
  int rowBase = blockIdx.x * 128;

  float4 acc0[8], acc1[8];
#pragma unroll
  for (int j = 0; j < 8; ++j) {
    acc0[j] = make_float4(0.f, 0.f, 0.f, 0.f);
    acc1[j] = make_float4(0.f, 0.f, 0.f, 0.f);
  }

  for (int kc = 0; kc < 4; ++kc) {
#pragma unroll
    for (int m = 0; m < 4; ++m) {
      int l = tid + 256 * m;
      int r = l >> 3;
      int u = l & 7;
      int gr = rowBase + r;
      float4 v = make_float4(0.f, 0.f, 0.f, 0.f);
      if (gr < M) v = *(const float4*)&x[(size_t)gr * 128 + kc * 32 + u * 4];
      int swz = u ^ ((r >> 3) & 7);
      *(float4*)&xs[r * 32 + swz * 4] = v;
    }
#pragma unroll
    for (int m = 0; m < 4; ++m) {
      int l = tid + 256 * m;
      int k = l >> 5;
      int u = l & 31;
      *(float4*)&Wl[k * 128 + u * 4] = *(const float4*)&W[(size_t)(kc * 32 + k) * 128 + u * 4];
    }
    __syncthreads();

#pragma unroll
    for (int k4 = 0; k4 < 32; k4 += 4) {
      float4 xa[8];
      int swz = (k4 >> 2) ^ (rg & 7);
#pragma unroll
      for (int j = 0; j < 8; ++j) {
        xa[j] = *(float4*)&xs[(rg * 8 + j) * 32 + swz * 4];
      }
#pragma unroll
      for (int kk = 0; kk < 4; ++kk) {
        float4 wb0 = *(float4*)&Wl[(k4 + kk) * 128 + cg * 8];
        float4 wb1 = *(float4*)&Wl[(k4 + kk) * 128 + cg * 8 + 4];
#pragma unroll
        for (int j = 0; j < 8; ++j) {
          float s = (kk == 0) ? xa[j].x : (kk == 1) ? xa[j].y : (kk == 2) ? xa[j].z : xa[j].w;
          fma4(acc0[j], s, wb0);
          fma4(acc1[j], s, wb1);
        }
      }
    }
    __syncthreads();
  }

#pragma unroll
  for (int j = 0; j < 8; ++j) {
    int gr = rowBase + rg * 8 + j;
    if (gr < M) {
      *(float4*)&xw[(size_t)gr * 128 + cg * 8] = acc0[j];
      *(float4*)&xw[(size_t)gr * 128 + cg * 8 + 4] = acc1[j];
      if (xwh) {
        uint4 p;
        p.x = pack_bf16x2(acc0[j].x, acc0[j].y);
        p.y = pack_bf16x2(acc0[j].z, acc0[j].w);
        p.z = pack_bf16x2(acc1[j].x, acc1[j].y);
        p.w = pack_bf16x2(acc1[j].z, acc1[j].w);
        *(uint4*)&xwh[(size_t)gr * 128 + cg * 8] = p;
      }
    }
  }
}

// --- K6: per-node gather-accumulate (1 wave per node) ---
template <int USE_BF16>
__global__ __launch_bounds__(256) void accum_kernel(const float* __restrict__ xw,
                                                    const unsigned short* __restrict__ xwh,
                                                    const int* __restrict__ srcidx,
                                                    const int* __restrict__ offsets,
                                                    const int* __restrict__ cnt,
                                                    const float* __restrict__ dinv,
                                                    const float* __restrict__ bias,
                                                    float* __restrict__ out, int N) {
  int wave = (int)(blockIdx.x * (blockDim.x >> 6)) + (threadIdx.x >> 6);
  int lane = threadIdx.x & 63;
  if (wave >= N) return;
  int i = wave;
  float di = dinv[i];
  int off = offsets[i];
  int deg = cnt[i];

  // self-loop term in fp32 (norm = dinv_i^2 can be 1.0 for isolated nodes)
  const float2* xws = (const float2*)(xw + (size_t)i * 128);
  float2 self = xws[lane];
  float sn = di * di;
  float2 acc;
  acc.x = self.x * sn;
  acc.y = self.y * sn;

  int j = 0;
  while (j < deg) {
    int batch = min(64, deg - j);
    int r = 0;
    float dv = 0.f;
    if (lane < batch) {
      r = srcidx[off + j + lane];
      dv = dinv[r];
    }
    for (int t = 0; t < batch; ++t) {
      int rs = __shfl(r, t);
      float norm = __shfl(dv, t) * di;
      if (USE_BF16) {
        const unsigned* xr = (const unsigned*)(xwh + (size_t)rs * 128);
        unsigned v = xr[lane];
        acc.x = fmaf(__uint_as_float(v << 16), norm, acc.x);
        acc.y = fmaf(__uint_as_float(v & 0xFFFF0000u), norm, acc.y);
      } else {
        const float2* xr = (const float2*)(xw + (size_t)rs * 128);
        float2 v = xr[lane];
        acc.x = fmaf(v.x, norm, acc.x);
        acc.y = fmaf(v.y, norm, acc.y);
      }
    }
    j += batch;
  }

  float2 bb = ((const float2*)bias)[lane];
  acc.x = fmaxf(acc.x + bb.x, 0.f);
  acc.y = fmaxf(acc.y + bb.y, 0.f);
  ((float2*)(out + (size_t)i * 128))[lane] = acc;
}

extern "C" void kernel_launch(void* const* d_in, const int* in_sizes, int n_in,
                              void* d_out, int out_size, void* d_ws, size_t ws_size,
                              hipStream_t stream) {
  const float* x = (const float*)d_in[0];
  const int* edge = (const int*)d_in[1];
  const float* W = (const float*)d_in[2];
  const float* b = (const float*)d_in[3];
  float* out = (float*)d_out;

  int N = in_sizes[0] / 128;  // 100000
  int E = in_sizes[1] / 2;    // 1600000
  const int* row = edge;      // sources
  const int* col = edge + E;  // targets
  int NB = (N + BNODES - 1) >> BSHIFT;  // 391 (<= NB_MAX)
  int chunk = (E + NBLK - 1) / NBLK;    // 6250

  // workspace layout
  char* ws = (char*)d_ws;
  size_t off = 0;
  auto alloc = [&](size_t bytes) -> void* {
    off = (off + 255) & ~(size_t)255;
    void* p = ws + off;
    off += bytes;
    return p;
  };
  float* xw = (float*)alloc((size_t)N * 128 * sizeof(float));  // 51.2 MB
  int* cnt = (int*)alloc((size_t)N * sizeof(int));
  int* offs = (int*)alloc((size_t)N * sizeof(int));
  float* dinv = (float*)alloc((size_t)N * sizeof(float));
  int* srcidx = (int*)alloc((size_t)E * sizeof(int));
  int* hist2d = (int*)alloc((size_t)NB * NBLK * sizeof(int));  // 400 KB
  int* btot = (int*)alloc((size_t)NB * sizeof(int));
  int* bbase = (int*)alloc((size_t)(NB + 1) * sizeof(int));
  // bins aliases xw: bins live K3->K4, xw live K5->K6 (stream-serial => safe)
  unsigned* bins = (unsigned*)xw;
  // bf16 mirror, only if workspace allows
  size_t need_xwh = ((off + 255) & ~(size_t)255) + (size_t)N * 128 * sizeof(unsigned short);
  unsigned short* xwh = nullptr;
  if (ws_size >= need_xwh) xwh = (unsigned short*)alloc((size_t)N * 128 * sizeof(unsigned short));

  hist2d_kernel<<<NBLK, 256, 0, stream>>>(col, hist2d, E, NB, chunk);
  scan_bucket<<<NB, 256, 0, stream>>>(hist2d, btot);
  scan_btot<<<1, 512, 0, stream>>>(btot, bbase, NB, E);
  scatter2_kernel<<<NBLK, 256, 0, stream>>>(row, col, hist2d, bbase, bins, E, NB, chunk);
  bucket_build<<<NB, 256, 0, stream>>>(bins, bbase, cnt, offs, dinv, srcidx, N);

  int gblocks = (N + 127) / 128;
  gemm_kernel<<<gblocks, 256, 0, stream>>>(x, W, xw, xwh, N);

  int nblocks = (N + 3) / 4;  // 4 waves per 256-thread block
  if (xwh)
    accum_kernel<1><<<nblocks, 256, 0, stream>>>(xw, xwh, srcidx, offs, cnt, dinv, b, out, N);
  else
    accum_kernel<0><<<nblocks, 256, 0, stream>>>(xw, xwh, srcidx, offs, cnt, dinv, b, out, N);
}

// Round 10
// 283.923 us; speedup vs baseline: 3.0320x; 1.1088x over previous
//
#include <hip/hip_runtime.h>
#include <hip/hip_bf16.h>

// GCN layer: out = relu(D^-1/2 (A+I) D^-1/2 (x@W) + b)
// N=100000 nodes, E=1.6M edges, d_in=d_out=128, fp32.
//
// Pipeline (atomic-free counting-sort CSR via 2D histogram, parallel scans):
//   K1 hist2d      : per-block LDS hist of 391 buckets -> hist2d[bucket][block]
//   K2a scan_bucket: per-bucket (391 blocks) exclusive scan of its 256 block
//                    counts (in-place) + bucket total -> btot
//   K2b scan_btot  : exclusive scan of 391 bucket totals -> bbase (1 block)
//   K3 scatter2    : block re-reads its chunk, scatters via LDS cursors
//                    (bbase[b] + within-bucket prefix), ZERO global atomics
//   K4 bucket_build: per bucket (1 block): LDS hist+scan -> cnt/offsets/dinv,
//                    LDS-cursor scatter -> srcidx
//   K5 gemm_kernel : xw = x @ W (fp32, 8x8 reg tile) + bf16 mirror xwh
//   K6 accum_kernel: per node (1 wave): acc = dinv_i^2*xw[i](fp32)
//                    + sum_e dinv[r]*dinv_i*xwh[r](bf16), 4x-unrolled gather
//                    for MLP; out = relu(acc + b)

#define BSHIFT 8              // 256 nodes per bucket
#define BNODES (1 << BSHIFT)
#define NB_MAX 512
#define NBLK 256              // scatter blocks (runs of ~16 elems = 1 cacheline)

__device__ __forceinline__ void fma4(float4& acc, float s, const float4& v) {
  acc.x = fmaf(s, v.x, acc.x);
  acc.y = fmaf(s, v.y, acc.y);
  acc.z = fmaf(s, v.z, acc.z);
  acc.w = fmaf(s, v.w, acc.w);
}

__device__ __forceinline__ unsigned pack_bf16x2(float a, float b) {
  unsigned ua = __float_as_uint(a), ub = __float_as_uint(b);
  ua += 0x7FFFu + ((ua >> 16) & 1u);  // RNE
  ub += 0x7FFFu + ((ub >> 16) & 1u);
  return (ua >> 16) | (ub & 0xFFFF0000u);
}

// --- K1: per-block bucket histogram -> hist2d[bucket*NBLK + block] ---
__global__ __launch_bounds__(256) void hist2d_kernel(const int* __restrict__ col,
                                                     int* __restrict__ hist2d,
                                                     int E, int NB, int chunk) {
  __shared__ int h[NB_MAX];
  int j = blockIdx.x;
  int lo = j * chunk;
  int hi = min(lo + chunk, E);
  for (int i = threadIdx.x; i < NB; i += 256) h[i] = 0;
  __syncthreads();
  for (int idx = lo + threadIdx.x; idx < hi; idx += 256)
    atomicAdd(&h[col[idx] >> BSHIFT], 1);
  __syncthreads();
  for (int i = threadIdx.x; i < NB; i += 256) hist2d[i * NBLK + j] = h[i];
}

// --- K2a: per-bucket exclusive scan over its 256 block counts (in place) ---
__global__ __launch_bounds__(256) void scan_bucket(int* __restrict__ hist2d,
                                                   int* __restrict__ btot) {
  __shared__ int s[256];
  int b = blockIdx.x;
  int tid = threadIdx.x;
  int v = hist2d[b * NBLK + tid];
  s[tid] = v;
  __syncthreads();
  for (int off = 1; off < 256; off <<= 1) {
    int t = (tid >= off) ? s[tid - off] : 0;
    __syncthreads();
    s[tid] += t;
    __syncthreads();
  }
  hist2d[b * NBLK + tid] = s[tid] - v;  // exclusive within-bucket prefix
  if (tid == 255) btot[b] = s[tid];
}

// --- K2b: exclusive scan of bucket totals -> bbase (+ sentinel) ---
__global__ __launch_bounds__(512) void scan_btot(const int* __restrict__ btot,
                                                 int* __restrict__ bbase, int NB, int E) {
  __shared__ int s[512];
  int tid = threadIdx.x;
  int v = (tid < NB) ? btot[tid] : 0;
  s[tid] = v;
  __syncthreads();
  for (int off = 1; off < 512; off <<= 1) {
    int t = (tid >= off) ? s[tid - off] : 0;
    __syncthreads();
    s[tid] += t;
    __syncthreads();
  }
  if (tid < NB) bbase[tid] = s[tid] - v;
  if (tid == 0) bbase[NB] = E;  // sentinel
}

// --- K3: atomic-free scatter using reserved per-(block,bucket) ranges ---
__global__ __launch_bounds__(256) void scatter2_kernel(const int* __restrict__ row,
                                                       const int* __restrict__ col,
                                                       const int* __restrict__ hist2d,
                                                       const int* __restrict__ bbase,
                                                       unsigned* __restrict__ bins,
                                                       int E, int NB, int chunk) {
  __shared__ int cur[NB_MAX];
  int j = blockIdx.x;
  int lo = j * chunk;
  int hi = min(lo + chunk, E);
  for (int i = threadIdx.x; i < NB; i += 256)
    cur[i] = bbase[i] + hist2d[i * NBLK + j];
  __syncthreads();
  for (int idx = lo + threadIdx.x; idx < hi; idx += 256) {
    int c = col[idx];
    int r = row[idx];
    int p = atomicAdd(&cur[c >> BSHIFT], 1);  // LDS atomic only
    bins[p] = ((unsigned)(c & (BNODES - 1)) << 17) | (unsigned)r;
  }
}

// --- K4: per-bucket CSR build, everything in LDS ---
__global__ __launch_bounds__(256) void bucket_build(const unsigned* __restrict__ bins,
                                                    const int* __restrict__ bbase,
                                                    int* __restrict__ cnt,
                                                    int* __restrict__ offsets,
                                                    float* __restrict__ dinv,
                                                    int* __restrict__ srcidx, int N) {
  int b = blockIdx.x;
  int base = bbase[b];
  int nItems = bbase[b + 1] - base;
  __shared__ int h[BNODES];
  __shared__ int sc[BNODES];
  __shared__ int cur[BNODES];
  int tid = threadIdx.x;
  h[tid] = 0;
  __syncthreads();
  for (int i = tid; i < nItems; i += 256) atomicAdd(&h[bins[base + i] >> 17], 1);
  __syncthreads();
  int v = h[tid];
  sc[tid] = v;
  __syncthreads();
  for (int off = 1; off < 256; off <<= 1) {
    int t = (tid >= off) ? sc[tid - off] : 0;
    __syncthreads();
    sc[tid] += t;
    __syncthreads();
  }
  int excl = sc[tid] - v;
  cur[tid] = excl;
  int node = (b << BSHIFT) + tid;
  if (node < N) {
    cnt[node] = v;
    offsets[node] = base + excl;
    dinv[node] = rsqrtf((float)(v + 1));
  }
  __syncthreads();
  for (int i = tid; i < nItems; i += 256) {
    unsigned x = bins[base + i];
    int clow = x >> 17;
    int r = (int)(x & 0x1FFFFu);
    int p = atomicAdd(&cur[clow], 1);
    srcidx[base + p] = r;
  }
}

// --- K5: xw = x @ W (8x8 register tile) + optional bf16 mirror ---
__global__ __launch_bounds__(256) void gemm_kernel(const float* __restrict__ x,
                                                   const float* __restrict__ W,
                                                   float* __restrict__ xw,
                                                   unsigned short* __restrict__ xwh, int M) {
  __shared__ float xs[128 * 32];  // swizzled
  __shared__ float Wl[32 * 128];
  int tid = threadIdx.x;
  int rg = tid >> 4;
  int cg = tid & 15;
  int rowBase = blockIdx.x * 128;

  float4 acc0[8], acc1[8];
#pragma unroll
  for (int j = 0; j < 8; ++j) {
    acc0[j] = make_float4(0.f, 0.f, 0.f, 0.f);
    acc1[j] = make_float4(0.f, 0.f, 0.f, 0.f);
  }

  for (int kc = 0; kc < 4; ++kc) {
#pragma unroll
    for (int m = 0; m < 4; ++m) {
      int l = tid + 256 * m;
      int r = l >> 3;
      int u = l & 7;
      int gr = rowBase + r;
      float4 v = make_float4(0.f, 0.f, 0.f, 0.f);
      if (gr < M) v = *(const float4*)&x[(size_t)gr * 128 + kc * 32 + u * 4];
      int swz = u ^ ((r >> 3) & 7);
      *(float4*)&xs[r * 32 + swz * 4] = v;
    }
#pragma unroll
    for (int m = 0; m < 4; ++m) {
      int l = tid + 256 * m;
      int k = l >> 5;
      int u = l & 31;
      *(float4*)&Wl[k * 128 + u * 4] = *(const float4*)&W[(size_t)(kc * 32 + k) * 128 + u * 4];
    }
    __syncthreads();

#pragma unroll
    for (int k4 = 0; k4 < 32; k4 += 4) {
      float4 xa[8];
      int swz = (k4 >> 2) ^ (rg & 7);
#pragma unroll
      for (int j = 0; j < 8; ++j) {
        xa[j] = *(float4*)&xs[(rg * 8 + j) * 32 + swz * 4];
      }
#pragma unroll
      for (int kk = 0; kk < 4; ++kk) {
        float4 wb0 = *(float4*)&Wl[(k4 + kk) * 128 + cg * 8];
        float4 wb1 = *(float4*)&Wl[(k4 + kk) * 128 + cg * 8 + 4];
#pragma unroll
        for (int j = 0; j < 8; ++j) {
          float s = (kk == 0) ? xa[j].x : (kk == 1) ? xa[j].y : (kk == 2) ? xa[j].z : xa[j].w;
          fma4(acc0[j], s, wb0);
          fma4(acc1[j], s, wb1);
        }
      }
    }
    __syncthreads();
  }

#pragma unroll
  for (int j = 0; j < 8; ++j) {
    int gr = rowBase + rg * 8 + j;
    if (gr < M) {
      *(float4*)&xw[(size_t)gr * 128 + cg * 8] = acc0[j];
      *(float4*)&xw[(size_t)gr * 128 + cg * 8 + 4] = acc1[j];
      if (xwh) {
        uint4 p;
        p.x = pack_bf16x2(acc0[j].x, acc0[j].y);
        p.y = pack_bf16x2(acc0[j].z, acc0[j].w);
        p.z = pack_bf16x2(acc1[j].x, acc1[j].y);
        p.w = pack_bf16x2(acc1[j].z, acc1[j].w);
        *(uint4*)&xwh[(size_t)gr * 128 + cg * 8] = p;
      }
    }
  }
}

// --- K6: per-node gather-accumulate (1 wave per node), 4x-unrolled MLP ---
template <int USE_BF16>
__global__ __launch_bounds__(256) void accum_kernel(const float* __restrict__ xw,
                                                    const unsigned short* __restrict__ xwh,
                                                    const int* __restrict__ srcidx,
                                                    const int* __restrict__ offsets,
                                                    const int* __restrict__ cnt,
                                                    const float* __restrict__ dinv,
                                                    const float* __restrict__ bias,
                                                    float* __restrict__ out, int N) {
  int wave = (int)(blockIdx.x * (blockDim.x >> 6)) + (threadIdx.x >> 6);
  int lane = threadIdx.x & 63;
  if (wave >= N) return;
  int i = wave;
  float di = dinv[i];
  int off = offsets[i];
  int deg = cnt[i];

  // self-loop term in fp32 (norm = dinv_i^2 can be 1.0 for isolated nodes)
  const float2* xws = (const float2*)(xw + (size_t)i * 128);
  float2 self = xws[lane];
  float sn = di * di;
  float2 acc;
  acc.x = self.x * sn;
  acc.y = self.y * sn;

  int j = 0;
  while (j < deg) {
    int batch = min(64, deg - j);
    int r = 0;
    float dv = 0.f;
    if (lane < batch) {
      r = srcidx[off + j + lane];
      dv = dinv[r];
    }
    int t = 0;
    // 4 independent row-gathers in flight per iteration (latency hiding)
    for (; t + 4 <= batch; t += 4) {
      int rs0 = __shfl(r, t + 0), rs1 = __shfl(r, t + 1);
      int rs2 = __shfl(r, t + 2), rs3 = __shfl(r, t + 3);
      float n0 = __shfl(dv, t + 0) * di, n1 = __shfl(dv, t + 1) * di;
      float n2 = __shfl(dv, t + 2) * di, n3 = __shfl(dv, t + 3) * di;
      if (USE_BF16) {
        unsigned v0 = ((const unsigned*)(xwh + (size_t)rs0 * 128))[lane];
        unsigned v1 = ((const unsigned*)(xwh + (size_t)rs1 * 128))[lane];
        unsigned v2 = ((const unsigned*)(xwh + (size_t)rs2 * 128))[lane];
        unsigned v3 = ((const unsigned*)(xwh + (size_t)rs3 * 128))[lane];
        acc.x = fmaf(__uint_as_float(v0 << 16), n0, acc.x);
        acc.y = fmaf(__uint_as_float(v0 & 0xFFFF0000u), n0, acc.y);
        acc.x = fmaf(__uint_as_float(v1 << 16), n1, acc.x);
        acc.y = fmaf(__uint_as_float(v1 & 0xFFFF0000u), n1, acc.y);
        acc.x = fmaf(__uint_as_float(v2 << 16), n2, acc.x);
        acc.y = fmaf(__uint_as_float(v2 & 0xFFFF0000u), n2, acc.y);
        acc.x = fmaf(__uint_as_float(v3 << 16), n3, acc.x);
        acc.y = fmaf(__uint_as_float(v3 & 0xFFFF0000u), n3, acc.y);
      } else {
        float2 v0 = ((const float2*)(xw + (size_t)rs0 * 128))[lane];
        float2 v1 = ((const float2*)(xw + (size_t)rs1 * 128))[lane];
        float2 v2 = ((const float2*)(xw + (size_t)rs2 * 128))[lane];
        float2 v3 = ((const float2*)(xw + (size_t)rs3 * 128))[lane];
        acc.x = fmaf(v0.x, n0, acc.x);
        acc.y = fmaf(v0.y, n0, acc.y);
        acc.x = fmaf(v1.x, n1, acc.x);
        acc.y = fmaf(v1.y, n1, acc.y);
        acc.x = fmaf(v2.x, n2, acc.x);
        acc.y = fmaf(v2.y, n2, acc.y);
        acc.x = fmaf(v3.x, n3, acc.x);
        acc.y = fmaf(v3.y, n3, acc.y);
      }
    }
    for (; t < batch; ++t) {
      int rs = __shfl(r, t);
      float norm = __shfl(dv, t) * di;
      if (USE_BF16) {
        unsigned v = ((const unsigned*)(xwh + (size_t)rs * 128))[lane];
        acc.x = fmaf(__uint_as_float(v << 16), norm, acc.x);
        acc.y = fmaf(__uint_as_float(v & 0xFFFF0000u), norm, acc.y);
      } else {
        float2 v = ((const float2*)(xw + (size_t)rs * 128))[lane];
        acc.x = fmaf(v.x, norm, acc.x);
        acc.y = fmaf(v.y, norm, acc.y);
      }
    }
    j += batch;
  }

  float2 bb = ((const float2*)bias)[lane];
  acc.x = fmaxf(acc.x + bb.x, 0.f);
  acc.y = fmaxf(acc.y + bb.y, 0.f);
  ((float2*)(out + (size_t)i * 128))[lane] = acc;
}

extern "C" void kernel_launch(void* const* d_in, const int* in_sizes, int n_in,
                              void* d_out, int out_size, void* d_ws, size_t ws_size,
                              hipStream_t stream) {
  const float* x = (const float*)d_in[0];
  const int* edge = (const int*)d_in[1];
  const float* W = (const float*)d_in[2];
  const float* b = (const float*)d_in[3];
  float* out = (float*)d_out;

  int N = in_sizes[0] / 128;  // 100000
  int E = in_sizes[1] / 2;    // 1600000
  const int* row = edge;      // sources
  const int* col = edge + E;  // targets
  int NB = (N + BNODES - 1) >> BSHIFT;  // 391 (<= NB_MAX)
  int chunk = (E + NBLK - 1) / NBLK;    // 6250

  // workspace layout
  char* ws = (char*)d_ws;
  size_t off = 0;
  auto alloc = [&](size_t bytes) -> void* {
    off = (off + 255) & ~(size_t)255;
    void* p = ws + off;
    off += bytes;
    return p;
  };
  float* xw = (float*)alloc((size_t)N * 128 * sizeof(float));  // 51.2 MB
  int* cnt = (int*)alloc((size_t)N * sizeof(int));
  int* offs = (int*)alloc((size_t)N * sizeof(int));
  float* dinv = (float*)alloc((size_t)N * sizeof(float));
  int* srcidx = (int*)alloc((size_t)E * sizeof(int));
  int* hist2d = (int*)alloc((size_t)NB * NBLK * sizeof(int));  // 400 KB
  int* btot = (int*)alloc((size_t)NB * sizeof(int));
  int* bbase = (int*)alloc((size_t)(NB + 1) * sizeof(int));
  // bins aliases xw: bins live K3->K4, xw live K5->K6 (stream-serial => safe)
  unsigned* bins = (unsigned*)xw;
  // bf16 mirror, only if workspace allows
  size_t need_xwh = ((off + 255) & ~(size_t)255) + (size_t)N * 128 * sizeof(unsigned short);
  unsigned short* xwh = nullptr;
  if (ws_size >= need_xwh) xwh = (unsigned short*)alloc((size_t)N * 128 * sizeof(unsigned short));

  hist2d_kernel<<<NBLK, 256, 0, stream>>>(col, hist2d, E, NB, chunk);
  scan_bucket<<<NB, 256, 0, stream>>>(hist2d, btot);
  scan_btot<<<1, 512, 0, stream>>>(btot, bbase, NB, E);
  scatter2_kernel<<<NBLK, 256, 0, stream>>>(row, col, hist2d, bbase, bins, E, NB, chunk);
  bucket_build<<<NB, 256, 0, stream>>>(bins, bbase, cnt, offs, dinv, srcidx, N);

  int gblocks = (N + 127) / 128;
  gemm_kernel<<<gblocks, 256, 0, stream>>>(x, W, xw, xwh, N);

  int nblocks = (N + 3) / 4;  // 4 waves per 256-thread block
  if (xwh)
    accum_kernel<1><<<nblocks, 256, 0, stream>>>(xw, xwh, srcidx, offs, cnt, dinv, b, out, N);
  else
    accum_kernel<0><<<nblocks, 256, 0, stream>>>(xw, xwh, srcidx, offs, cnt, dinv, b, out, N);
}